// Round 7
// baseline (81.413 us; speedup 1.0000x reference)
//
#include <hip/hip_runtime.h>

#define CLS 64
#define DIM 256
#define NB  256          // main-kernel blocks / partial slots (1 per CU)
#define WIN 1024         // rows per block window
#define WPB 16           // waves per block
#define CPW 4            // classes per wave (CLS / WPB)
#define P2  4            // reduce1 parts per class

typedef float f32x4 __attribute__((ext_vector_type(4)));

// ---- wave64 sum via DPP (VALU pipe); result uniform across all lanes ----
__device__ __forceinline__ float wave_sum64(float f) {
    int t;
    t = __builtin_amdgcn_update_dpp(0, __float_as_int(f), 0x111, 0xf, 0xf, false); f += __int_as_float(t); // row_shr:1
    t = __builtin_amdgcn_update_dpp(0, __float_as_int(f), 0x112, 0xf, 0xf, false); f += __int_as_float(t); // row_shr:2
    t = __builtin_amdgcn_update_dpp(0, __float_as_int(f), 0x114, 0xf, 0xe, false); f += __int_as_float(t); // row_shr:4
    t = __builtin_amdgcn_update_dpp(0, __float_as_int(f), 0x118, 0xf, 0xc, false); f += __int_as_float(t); // row_shr:8
    t = __builtin_amdgcn_update_dpp(0, __float_as_int(f), 0x142, 0xa, 0xf, false); f += __int_as_float(t); // row_bcast:15
    t = __builtin_amdgcn_update_dpp(0, __float_as_int(f), 0x143, 0xc, 0xf, false); f += __int_as_float(t); // row_bcast:31
    return __int_as_float(__builtin_amdgcn_readlane(__float_as_int(f), 63));
}

// ---- main: sequential-window stream; per-wave register class accumulators ----
__global__ __launch_bounds__(1024) void k_main(
    const float* __restrict__ emb, const int* __restrict__ labels, int N,
    float* __restrict__ partials,   // [CLS][NB][DIM]
    float* __restrict__ cnts)       // [CLS][NB]
{
    __shared__ unsigned short lst[WPB][WIN];   // 32 KB: row indices bucketed by owner wave
    __shared__ unsigned char  labk[WIN];       // class & 3 per row
    __shared__ int lcnt[WPB];

    const int tid  = threadIdx.x;
    const int w    = tid >> 6;                 // wave id: owns classes 4w..4w+3
    const int lane = tid & 63;                 // lane l owns dims [4l, 4l+4)

    f32x4 a0 = {0,0,0,0}, a1 = {0,0,0,0}, a2 = {0,0,0,0}, a3 = {0,0,0,0};
    float c0 = 0.f, c1 = 0.f, c2 = 0.f, c3 = 0.f;

    for (int wb = blockIdx.x; (long long)wb * WIN < (long long)N; wb += NB) {
        const int base  = wb * WIN;
        const int nrows = min(WIN, N - base);
        __syncthreads();                       // protect lst/labk from prior window's walk
        if (tid < WPB) lcnt[tid] = 0;
        __syncthreads();
        if (tid < nrows) {                     // bucket rows by owner wave (coalesced label read)
            const int c = labels[base + tid];
            labk[tid] = (unsigned char)(c & (CPW - 1));
            const int p = atomicAdd(&lcnt[c >> 2], 1);
            lst[c >> 2][p] = (unsigned short)tid;
        }
        __syncthreads();

        const int n = lcnt[w];
        // 2-deep software pipeline: next row's load in flight during current norm
        int   r = (n > 0) ? (int)lst[w][0] : 0;
        f32x4 v = {0,0,0,0};
        if (n > 0) v = *(reinterpret_cast<const f32x4*>(emb + (size_t)(base + r) * DIM) + lane);
        for (int j = 0; j < n; ++j) {
            const bool more = (j + 1 < n);
            const int  rn = more ? (int)lst[w][j + 1] : 0;
            f32x4 vn = {0,0,0,0};
            if (more) vn = *(reinterpret_cast<const f32x4*>(emb + (size_t)(base + rn) * DIM) + lane);
            const float ss  = wave_sum64(v.x*v.x + v.y*v.y + v.z*v.z + v.w*v.w);
            const float inv = 1.0f / fmaxf(sqrtf(ss), 1e-12f);
            const int   k   = labk[r];                         // wave-uniform
            const float tx = v.x*inv, ty = v.y*inv, tz = v.z*inv, tw = v.w*inv;
            if      (k == 0) { a0.x += tx; a0.y += ty; a0.z += tz; a0.w += tw; c0 += 1.f; }
            else if (k == 1) { a1.x += tx; a1.y += ty; a1.z += tz; a1.w += tw; c1 += 1.f; }
            else if (k == 2) { a2.x += tx; a2.y += ty; a2.z += tz; a2.w += tw; c2 += 1.f; }
            else             { a3.x += tx; a3.y += ty; a3.z += tz; a3.w += tw; c3 += 1.f; }
            r = rn; v = vn;
        }
    }

    // epilogue: this block's per-class partial sums + counts (coalesced 1 KB stores)
    const int b = blockIdx.x;
    {
        float* p = partials + ((size_t)(w * CPW + 0) * NB + b) * DIM + 4 * lane;
        *reinterpret_cast<f32x4*>(p) = a0;
        p = partials + ((size_t)(w * CPW + 1) * NB + b) * DIM + 4 * lane;
        *reinterpret_cast<f32x4*>(p) = a1;
        p = partials + ((size_t)(w * CPW + 2) * NB + b) * DIM + 4 * lane;
        *reinterpret_cast<f32x4*>(p) = a2;
        p = partials + ((size_t)(w * CPW + 3) * NB + b) * DIM + 4 * lane;
        *reinterpret_cast<f32x4*>(p) = a3;
        if (lane == 0) {
            cnts[(size_t)(w * CPW + 0) * NB + b] = c0;
            cnts[(size_t)(w * CPW + 1) * NB + b] = c1;
            cnts[(size_t)(w * CPW + 2) * NB + b] = c2;
            cnts[(size_t)(w * CPW + 3) * NB + b] = c3;
        }
    }
}

// ---- reduce1: fold the NB block-partials to P2 chunks per class (coalesced) ----
__global__ __launch_bounds__(256) void k_reduce1(
    const float* __restrict__ partials, float* __restrict__ red1)
{
    const int c = blockIdx.x >> 2;             // / P2
    const int p = blockIdx.x & (P2 - 1);
    const int d = threadIdx.x;                 // 256 threads = one dim each
    const float* src = partials + ((size_t)c * NB + p * (NB / P2)) * DIM + d;
    float s = 0.f;
    #pragma unroll 8
    for (int b = 0; b < NB / P2; ++b) s += src[(size_t)b * DIM];
    red1[((size_t)c * P2 + p) * DIM + d] = s;
}

// ---- per-class loss ----
__global__ __launch_bounds__(256) void k_classloss(
    const float* __restrict__ red1, const float* __restrict__ cnts,
    float* __restrict__ closs, float* __restrict__ cvalid)
{
    const int c = blockIdx.x;   // 64 blocks
    const int d = threadIdx.x;  // 256 threads
    float s = 0.f;
    #pragma unroll
    for (int p = 0; p < P2; ++p) s += red1[((size_t)c * P2 + p) * DIM + d];
    const float w2 = wave_sum64(s * s);
    const float cw = wave_sum64(cnts[(size_t)c * NB + d]);   // NB==256 block-counts
    __shared__ float reds[4], redc[4];
    if ((d & 63) == 0) { reds[d >> 6] = w2; redc[d >> 6] = cw; }
    __syncthreads();
    if (d == 0) {
        float s2   = reds[0] + reds[1] + reds[2] + reds[3];  // ||sums_c||^2
        float cnt  = redc[0] + redc[1] + redc[2] + redc[3];
        float invc = 1.0f / fmaxf(cnt, 1.0f);
        float cn   = sqrtf(s2) * invc;                       // ||center_raw||
        float dot  = s2 * invc / fmaxf(cn, 1e-12f);          // sum over class of sim
        float pcs  = cnt - dot;                              // sum over class of (1 - sim)
        bool valid = cnt > 1.0f;
        closs[c]  = valid ? pcs * invc : 0.0f;
        cvalid[c] = valid ? 1.0f : 0.0f;
    }
}

// ---- final scalar ----
__global__ void k_final(const float* __restrict__ closs, const float* __restrict__ cvalid,
                        const int* __restrict__ epoch, float* __restrict__ out)
{
    const int t = threadIdx.x;  // 64
    const float sl = wave_sum64(closs[t]);
    const float nv = wave_sum64(cvalid[t]);
    if (t == 0) {
        float res = (nv > 0.0f) ? (sl / fmaxf(nv, 1.0f)) : 0.0f;
        if (epoch[0] < 1) res = 0.0f;   // START guard
        out[0] = res;
    }
}

extern "C" void kernel_launch(void* const* d_in, const int* in_sizes, int n_in,
                              void* d_out, int out_size, void* d_ws, size_t ws_size,
                              hipStream_t stream)
{
    const float* emb    = (const float*)d_in[0];
    const int*   labels = (const int*)d_in[1];
    const int*   epoch  = (const int*)d_in[2];
    float*       out    = (float*)d_out;
    const int N = in_sizes[0] / DIM;

    // workspace carve-up (all regions fully written before read, every call)
    char* ws = (char*)d_ws;
    size_t off = 0;
    auto carve = [&](size_t bytes) { size_t o = off; off = (off + bytes + 255) & ~(size_t)255; return o; };
    float* partials = (float*)(ws + carve((size_t)CLS * NB * DIM * sizeof(float)));  // 16 MB
    float* cnts     = (float*)(ws + carve((size_t)CLS * NB * sizeof(float)));        // 64 KB
    float* red1     = (float*)(ws + carve((size_t)CLS * P2 * DIM * sizeof(float)));  // 256 KB
    float* closs    = (float*)(ws + carve((size_t)CLS * sizeof(float)));
    float* cvalid   = (float*)(ws + carve((size_t)CLS * sizeof(float)));
    (void)ws_size;  // ~16.4 MB needed; harness provides ~1 GiB (observed via poison fill)

    k_main     <<<NB,       1024, 0, stream>>>(emb, labels, N, partials, cnts);
    k_reduce1  <<<CLS * P2, 256,  0, stream>>>(partials, red1);
    k_classloss<<<CLS,      256,  0, stream>>>(red1, cnts, closs, cvalid);
    k_final    <<<1,        64,   0, stream>>>(closs, cvalid, epoch, out);
}

// Round 8
// 61.903 us; speedup vs baseline: 1.3152x; 1.3152x over previous
//
#include <hip/hip_runtime.h>

#define CLS   64
#define DIM   256
#define PARTS 8           // classsum blocks per class
#define HB    256         // hist / scatter blocks
#define HT    256         // their threads

typedef float f32x4 __attribute__((ext_vector_type(4)));

// ---- wave64 sum via DPP (VALU pipe); result uniform across all lanes ----
__device__ __forceinline__ float wave_sum64(float f) {
    int t;
    t = __builtin_amdgcn_update_dpp(0, __float_as_int(f), 0x111, 0xf, 0xf, false); f += __int_as_float(t); // row_shr:1
    t = __builtin_amdgcn_update_dpp(0, __float_as_int(f), 0x112, 0xf, 0xf, false); f += __int_as_float(t); // row_shr:2
    t = __builtin_amdgcn_update_dpp(0, __float_as_int(f), 0x114, 0xf, 0xe, false); f += __int_as_float(t); // row_shr:4
    t = __builtin_amdgcn_update_dpp(0, __float_as_int(f), 0x118, 0xf, 0xc, false); f += __int_as_float(t); // row_shr:8
    t = __builtin_amdgcn_update_dpp(0, __float_as_int(f), 0x142, 0xa, 0xf, false); f += __int_as_float(t); // row_bcast:15
    t = __builtin_amdgcn_update_dpp(0, __float_as_int(f), 0x143, 0xc, 0xf, false); f += __int_as_float(t); // row_bcast:31
    return __int_as_float(__builtin_amdgcn_readlane(__float_as_int(f), 63));
}

// ---- S1: per-block label histogram -> hist[HB][CLS] ----
__global__ __launch_bounds__(HT) void k_hist(const int* __restrict__ labels, int N,
                                             int* __restrict__ hist)
{
    __shared__ int h[CLS];
    if (threadIdx.x < CLS) h[threadIdx.x] = 0;
    __syncthreads();
    const int chunk = (N + gridDim.x - 1) / gridDim.x;
    const int s = blockIdx.x * chunk;
    const int e = min(N, s + chunk);
    for (int i = s + threadIdx.x; i < e; i += blockDim.x)
        atomicAdd(&h[labels[i]], 1);
    __syncthreads();
    if (threadIdx.x < CLS) hist[blockIdx.x * CLS + threadIdx.x] = h[threadIdx.x];
}

// ---- S2: scatter with locally re-derived prefixes (no scan kernel, no global atomics) ----
__global__ __launch_bounds__(HT) void k_scatter2(
    const int* __restrict__ labels, int N,
    const int* __restrict__ hist,      // [HB][CLS]
    int* __restrict__ cstart,          // [CLS+1], written by block 0
    int* __restrict__ bucket)
{
    __shared__ int t4[4][CLS], p4[4][CLS];   // quarter partials
    __shared__ int tot[CLS], pre[CLS], cur[CLS];
    const int tid = threadIdx.x;
    const int c = tid & 63, q = tid >> 6;    // 4 quarters over the 256 hist rows
    int t = 0, p = 0;
    const int myb = blockIdx.x;
    #pragma unroll 4
    for (int b = q * (HB / 4); b < (q + 1) * (HB / 4); ++b) {
        const int v = hist[b * CLS + c];     // L2-hot (64 KB table shared by all blocks)
        t += v;
        if (b < myb) p += v;
    }
    t4[q][c] = t; p4[q][c] = p;
    __syncthreads();
    if (tid < CLS) {
        tot[tid] = t4[0][tid] + t4[1][tid] + t4[2][tid] + t4[3][tid];
        pre[tid] = p4[0][tid] + p4[1][tid] + p4[2][tid] + p4[3][tid];
    }
    __syncthreads();
    if (tid == 0) {
        int acc = 0;
        for (int j = 0; j < CLS; ++j) { cur[j] = acc + pre[j]; acc += tot[j]; }
    }
    __syncthreads();
    if (myb == 0) {                          // publish class starts for downstream kernels
        if (tid < CLS) cstart[tid] = cur[tid] - pre[tid];
        if (tid == CLS) cstart[CLS] = N;
    }
    const int chunk = (N + gridDim.x - 1) / gridDim.x;   // MUST match k_hist's chunking
    const int s = myb * chunk;
    const int e = min(N, s + chunk);
    for (int i = s + tid; i < e; i += HT) {
        const int cc = labels[i];
        const int slot = atomicAdd(&cur[cc], 1);   // LDS atomic; order in class irrelevant
        bucket[slot] = i;
    }
}

// ---- S3: dense per-class reduction; 4 rows/wave/iter for in-flight depth ----
__global__ __launch_bounds__(1024) void k_classsum(
    const float* __restrict__ emb, const int* __restrict__ bucket,
    const int* __restrict__ cstart, float* __restrict__ partials)
{
    __shared__ float red[16 * 260];            // padded stride -> no bank conflicts
    const int c    = blockIdx.x >> 3;          // / PARTS
    const int part = blockIdx.x & (PARTS - 1);
    const int s0 = cstart[c], s1 = cstart[c + 1];
    const int ccnt = s1 - s0;
    const int p0 = s0 + (int)(((long long)ccnt * part) >> 3);
    const int p1 = s0 + (int)(((long long)ccnt * (part + 1)) >> 3);
    const int wid = threadIdx.x >> 6, lane = threadIdx.x & 63;
    const int cnt   = p1 - p0;
    const int nfull = cnt & ~63;               // rows handled 4-per-wave (16 waves x 4)

    f32x4 acc = {0.f, 0.f, 0.f, 0.f};

    // main: 4 independent 1 KB row loads in flight per wave; DPP norm chains interleave
    for (int j = p0 + 4 * wid; j < p0 + nfull; j += 64) {
        const int rA = bucket[j];
        const int rB = bucket[j + 1];
        const int rC = bucket[j + 2];
        const int rD = bucket[j + 3];
        const f32x4 a = *(reinterpret_cast<const f32x4*>(emb + (size_t)rA * DIM) + lane);
        const f32x4 b = *(reinterpret_cast<const f32x4*>(emb + (size_t)rB * DIM) + lane);
        const f32x4 g = *(reinterpret_cast<const f32x4*>(emb + (size_t)rC * DIM) + lane);
        const f32x4 d = *(reinterpret_cast<const f32x4*>(emb + (size_t)rD * DIM) + lane);
        const float sA = wave_sum64(a.x*a.x + a.y*a.y + a.z*a.z + a.w*a.w);
        const float sB = wave_sum64(b.x*b.x + b.y*b.y + b.z*b.z + b.w*b.w);
        const float sC = wave_sum64(g.x*g.x + g.y*g.y + g.z*g.z + g.w*g.w);
        const float sD = wave_sum64(d.x*d.x + d.y*d.y + d.z*d.z + d.w*d.w);
        const float iA = 1.0f / fmaxf(sqrtf(sA), 1e-12f);
        const float iB = 1.0f / fmaxf(sqrtf(sB), 1e-12f);
        const float iC = 1.0f / fmaxf(sqrtf(sC), 1e-12f);
        const float iD = 1.0f / fmaxf(sqrtf(sD), 1e-12f);
        acc.x += a.x*iA + b.x*iB + g.x*iC + d.x*iD;
        acc.y += a.y*iA + b.y*iB + g.y*iC + d.y*iD;
        acc.z += a.z*iA + b.z*iB + g.z*iC + d.z*iD;
        acc.w += a.w*iA + b.w*iB + g.w*iC + d.w*iD;
    }
    // tail: remaining (< 64) rows, one per wave stride-16
    for (int j = p0 + nfull + wid; j < p1; j += 16) {
        const int row = bucket[j];
        const f32x4 v = *(reinterpret_cast<const f32x4*>(emb + (size_t)row * DIM) + lane);
        const float ss = wave_sum64(v.x * v.x + v.y * v.y + v.z * v.z + v.w * v.w);
        const float inv = 1.0f / fmaxf(sqrtf(ss), 1e-12f);
        acc.x += v.x * inv; acc.y += v.y * inv; acc.z += v.z * inv; acc.w += v.w * inv;
    }

    float* my = &red[wid * 260 + 4 * lane];
    my[0] = acc.x; my[1] = acc.y; my[2] = acc.z; my[3] = acc.w;
    __syncthreads();
    if (threadIdx.x < DIM) {
        float s = 0.f;
        #pragma unroll
        for (int w = 0; w < 16; ++w) s += red[w * 260 + threadIdx.x];
        partials[(size_t)blockIdx.x * DIM + threadIdx.x] = s;
    }
}

// ---- S4: per-class loss (64 blocks: parallel partials read) ----
__global__ __launch_bounds__(256) void k_classloss(
    const float* __restrict__ partials, const int* __restrict__ cstart,
    float* __restrict__ closs, float* __restrict__ cvalid)
{
    const int c = blockIdx.x;   // 64 blocks
    const int d = threadIdx.x;  // 256 threads = one dim each
    float s = 0.f;
    #pragma unroll
    for (int p = 0; p < PARTS; ++p)
        s += partials[(size_t)(c * PARTS + p) * DIM + d];
    const float w = wave_sum64(s * s);
    __shared__ float red[4];
    if ((d & 63) == 0) red[d >> 6] = w;
    __syncthreads();
    if (d == 0) {
        float s2   = red[0] + red[1] + red[2] + red[3];   // ||sums_c||^2
        float cnt  = (float)(cstart[c + 1] - cstart[c]);
        float invc = 1.0f / fmaxf(cnt, 1.0f);
        float cn   = sqrtf(s2) * invc;                    // ||center_raw||
        float dot  = s2 * invc / fmaxf(cn, 1e-12f);       // sum over class of sim
        float pcs  = cnt - dot;                           // sum over class of (1 - sim)
        bool valid = cnt > 1.0f;
        closs[c]  = valid ? pcs * invc : 0.0f;
        cvalid[c] = valid ? 1.0f : 0.0f;
    }
}

// ---- S5: final scalar ----
__global__ void k_final(const float* __restrict__ closs, const float* __restrict__ cvalid,
                        const int* __restrict__ epoch, float* __restrict__ out)
{
    const int t = threadIdx.x;  // 64
    const float sl = wave_sum64(closs[t]);
    const float nv = wave_sum64(cvalid[t]);
    if (t == 0) {
        float res = (nv > 0.0f) ? (sl / fmaxf(nv, 1.0f)) : 0.0f;
        if (epoch[0] < 1) res = 0.0f;   // START guard
        out[0] = res;
    }
}

extern "C" void kernel_launch(void* const* d_in, const int* in_sizes, int n_in,
                              void* d_out, int out_size, void* d_ws, size_t ws_size,
                              hipStream_t stream)
{
    const float* emb    = (const float*)d_in[0];
    const int*   labels = (const int*)d_in[1];
    const int*   epoch  = (const int*)d_in[2];
    float*       out    = (float*)d_out;
    const int N = in_sizes[0] / DIM;

    // workspace carve-up (every region fully written before read each call)
    char* ws = (char*)d_ws;
    size_t off = 0;
    auto carve = [&](size_t bytes) { size_t o = off; off = (off + bytes + 255) & ~(size_t)255; return o; };
    int*   hist     = (int*)  (ws + carve((size_t)HB * CLS * sizeof(int)));
    int*   cstart   = (int*)  (ws + carve((size_t)(CLS + 1) * sizeof(int)));
    int*   bucket   = (int*)  (ws + carve((size_t)N * sizeof(int)));
    float* partials = (float*)(ws + carve((size_t)CLS * PARTS * DIM * sizeof(float)));
    float* closs    = (float*)(ws + carve((size_t)CLS * sizeof(float)));
    float* cvalid   = (float*)(ws + carve((size_t)CLS * sizeof(float)));
    (void)ws_size;  // requires ~1.6 MB; harness provides ~1 GiB (observed via poison fill)

    k_hist     <<<HB,          HT,   0, stream>>>(labels, N, hist);
    k_scatter2 <<<HB,          HT,   0, stream>>>(labels, N, hist, cstart, bucket);
    k_classsum <<<CLS * PARTS, 1024, 0, stream>>>(emb, bucket, cstart, partials);
    k_classloss<<<CLS,         256,  0, stream>>>(partials, cstart, closs, cvalid);
    k_final    <<<1,           64,   0, stream>>>(closs, cvalid, epoch, out);
}